// Round 2
// baseline (407.733 us; speedup 1.0000x reference)
//
#include <hip/hip_runtime.h>

// VoxelFeatureEncoding: voxels[20000,35,4] -> out[20000,35,128]
// out[:, :, :64]  = relu(BN(aug @ W^T + b)),  aug = [v, v[:3]-mean3]
// out[:, :, 64:]  = broadcast(max over T of first half)
//
// Algebra: dot(w_c, aug_t) = dot(weff_c, v_t) - dot(wrel_c, mean3)
//   weff_c[j] = w[c][j] + (j<3 ? w[c][4+j] : 0), wrel_c = w[c][4:7]
// BN scale folded into weff/wrel, shift carried separately. So encode needs
// only the raw float4 row + per-voxel mean3: 4 FMA per (t,c), no shuffle
// broadcast of row data (LDS-staged rows instead), float4 stores.

#define NVOX   20000
#define TDIM   35
#define NCH    128
#define HID    64
#define NTF    700000.0f      // N*T, exact in fp32
#define EPS    1e-5f
#define NBLK_A 256
#define PARAM_OFF (NBLK_A * 35)   // ws: [256*35 partials][64*8 params] = 37,888 B

// ---------------- pass 1: per-block partial [M2(28) | s(7)] ----------------
__global__ __launch_bounds__(256) void vfe_stats(const float* __restrict__ vox,
                                                 float* __restrict__ ws) {
  const int lane = threadIdx.x & 63;
  const int wid  = threadIdx.x >> 6;
  const int gwave  = (blockIdx.x * 256 + threadIdx.x) >> 6;
  const int nwaves = NBLK_A * 4;

  float m2[28], sv[7];
#pragma unroll
  for (int i = 0; i < 28; ++i) m2[i] = 0.f;
#pragma unroll
  for (int i = 0; i < 7; ++i) sv[i] = 0.f;

  for (int n = gwave; n < NVOX; n += nwaves) {
    float4 row = make_float4(0.f, 0.f, 0.f, 0.f);
    if (lane < TDIM) row = *(const float4*)(vox + (size_t)n * (TDIM * 4) + lane * 4);
    float rowsum = (row.x + row.y) + (row.z + row.w);
    float cnt = (float)__popcll(__ballot((lane < TDIM) && (rowsum != 0.f)));
    float s0 = row.x, s1 = row.y, s2 = row.z;
#pragma unroll
    for (int off = 32; off; off >>= 1) {
      s0 += __shfl_down(s0, off);
      s1 += __shfl_down(s1, off);
      s2 += __shfl_down(s2, off);
    }
    float rc = 1.f / cnt;
    float mx = __shfl(s0, 0) * rc;
    float my = __shfl(s1, 0) * rc;
    float mz = __shfl(s2, 0) * rc;
    if (lane < TDIM) {
      float a[7] = {row.x, row.y, row.z, row.w, row.x - mx, row.y - my, row.z - mz};
      int idx = 0;
#pragma unroll
      for (int j = 0; j < 7; ++j) {
        sv[j] += a[j];
#pragma unroll
        for (int k = j; k < 7; ++k) { m2[idx] = fmaf(a[j], a[k], m2[idx]); ++idx; }
      }
    }
  }

  __shared__ float part[4][35];
#pragma unroll
  for (int i = 0; i < 35; ++i) {
    float v = (i < 28) ? m2[i] : sv[i - 28];
#pragma unroll
    for (int off = 32; off; off >>= 1) v += __shfl_down(v, off);
    if (lane == 0) part[wid][i] = v;
  }
  __syncthreads();
  if (threadIdx.x < 35)
    ws[blockIdx.x * 35 + threadIdx.x] =
        part[0][threadIdx.x] + part[1][threadIdx.x] +
        part[2][threadIdx.x] + part[3][threadIdx.x];
}

// -- pass 2: BN stats -> per-channel folded params {scale*weff[4]},{scale*wrel[3],shift}
__global__ void vfe_bnparams(const float* __restrict__ W, const float* __restrict__ b,
                             const float* __restrict__ gamma, const float* __restrict__ beta,
                             float* __restrict__ ws) {
  __shared__ float stats[35];
  for (int i = threadIdx.x; i < 35; i += 64) {
    float acc = 0.f;
    for (int p = 0; p < NBLK_A; ++p) acc += ws[p * 35 + i];
    stats[i] = acc;
  }
  __syncthreads();

  const int c = threadIdx.x;
  float m2[7][7];
  {
    int idx = 0;
    for (int j = 0; j < 7; ++j)
      for (int k = j; k < 7; ++k) { float v = stats[idx++]; m2[j][k] = v; m2[k][j] = v; }
  }
  float w[7];
#pragma unroll
  for (int j = 0; j < 7; ++j) w[j] = W[c * 7 + j];
  float bc = b[c];

  float wdots = 0.f;
#pragma unroll
  for (int j = 0; j < 7; ++j) wdots = fmaf(w[j], stats[28 + j], wdots);
  float q = 0.f;
#pragma unroll
  for (int j = 0; j < 7; ++j) {
    float t = 0.f;
#pragma unroll
    for (int k = 0; k < 7; ++k) t = fmaf(w[k], m2[j][k], t);
    q = fmaf(w[j], t, q);
  }
  float sx  = wdots + NTF * bc;                       // sum x_c
  float sxx = q + 2.f * bc * wdots + NTF * bc * bc;   // sum x_c^2
  float mu  = sx / NTF;
  float var = sxx / NTF - mu * mu;                    // biased, as reference
  float scale = gamma[c] / sqrtf(var + EPS);
  float shift = beta[c] + scale * (bc - mu);          // linear bias folded in

  float* p = ws + PARAM_OFF + c * 8;
  p[0] = scale * (w[0] + w[4]);
  p[1] = scale * (w[1] + w[5]);
  p[2] = scale * (w[2] + w[6]);
  p[3] = scale * w[3];
  p[4] = scale * w[4];
  p[5] = scale * w[5];
  p[6] = scale * w[6];
  p[7] = shift;
}

// ---- pass 3: wave/voxel, lane=(tgroup, 4-channel group), float4 stores ----
__global__ __launch_bounds__(256) void vfe_encode(const float* __restrict__ vox,
                                                  const float* __restrict__ ws,
                                                  float* __restrict__ out) {
  const int lane = threadIdx.x & 63;
  const int wid  = threadIdx.x >> 6;
  const int n = (blockIdx.x * 256 + threadIdx.x) >> 6;

  __shared__ float4 rows[4][64];

  float4 row = make_float4(0.f, 0.f, 0.f, 0.f);
  if (lane < TDIM) row = *(const float4*)(vox + (size_t)n * (TDIM * 4) + lane * 4);
  float rowsum = (row.x + row.y) + (row.z + row.w);
  float cnt = (float)__popcll(__ballot((lane < TDIM) && (rowsum != 0.f)));
  float s0 = row.x, s1 = row.y, s2 = row.z;
#pragma unroll
  for (int off = 32; off; off >>= 1) {
    s0 += __shfl_down(s0, off);
    s1 += __shfl_down(s1, off);
    s2 += __shfl_down(s2, off);
  }
  float rc = 1.f / cnt;
  const float mx = __shfl(s0, 0) * rc;
  const float my = __shfl(s1, 0) * rc;
  const float mz = __shfl(s2, 0) * rc;

  rows[wid][lane] = row;
  __syncthreads();

  const int tg = lane >> 4;          // which t mod 4
  const int c4 = (lane & 15) << 2;   // first of 4 channels

  // per-channel folded params: wv = scale*weff (4), wr.xyz = scale*wrel, wr.w = shift
  const float4* pars = (const float4*)(ws + PARAM_OFF);
  float4 wv[4], wr[4];
  float base[4], agg[4];
#pragma unroll
  for (int i = 0; i < 4; ++i) {
    wv[i] = pars[(c4 + i) * 2];
    wr[i] = pars[(c4 + i) * 2 + 1];
    base[i] = wr[i].w - (wr[i].x * mx + wr[i].y * my + wr[i].z * mz);
    agg[i] = 0.f;  // post-ReLU values >= 0
  }

  float* op = out + (size_t)n * (TDIM * NCH);
#pragma unroll
  for (int k = 0; k < 9; ++k) {
    const int t = 4 * k + tg;
    if (t < TDIM) {
      float4 v = rows[wid][t];
      float y[4];
#pragma unroll
      for (int i = 0; i < 4; ++i) {
        float d = fmaf(wv[i].x, v.x, base[i]);
        d = fmaf(wv[i].y, v.y, d);
        d = fmaf(wv[i].z, v.z, d);
        d = fmaf(wv[i].w, v.w, d);
        d = fmaxf(d, 0.f);
        agg[i] = fmaxf(agg[i], d);
        y[i] = d;
      }
      *(float4*)(op + t * NCH + c4) = make_float4(y[0], y[1], y[2], y[3]);
    }
  }

  // max across the 4 t-groups holding the same channels (lanes ^16, ^32)
#pragma unroll
  for (int i = 0; i < 4; ++i) {
    agg[i] = fmaxf(agg[i], __shfl_xor(agg[i], 16));
    agg[i] = fmaxf(agg[i], __shfl_xor(agg[i], 32));
  }
  const float4 av = make_float4(agg[0], agg[1], agg[2], agg[3]);
#pragma unroll
  for (int k = 0; k < 9; ++k) {
    const int t = 4 * k + tg;
    if (t < TDIM) *(float4*)(op + t * NCH + HID + c4) = av;
  }
}

extern "C" void kernel_launch(void* const* d_in, const int* in_sizes, int n_in,
                              void* d_out, int out_size, void* d_ws, size_t ws_size,
                              hipStream_t stream) {
  const float* vox   = (const float*)d_in[0];
  const float* W     = (const float*)d_in[1];
  const float* b     = (const float*)d_in[2];
  const float* gamma = (const float*)d_in[3];
  const float* beta  = (const float*)d_in[4];
  float* out = (float*)d_out;
  float* ws  = (float*)d_ws;

  vfe_stats<<<NBLK_A, 256, 0, stream>>>(vox, ws);
  vfe_bnparams<<<1, 64, 0, stream>>>(W, b, gamma, beta, ws);
  vfe_encode<<<NVOX / 4, 256, 0, stream>>>(vox, ws, out);
}

// Round 4
// 389.353 us; speedup vs baseline: 1.0472x; 1.0472x over previous
//
#include <hip/hip_runtime.h>

// VoxelFeatureEncoding: voxels[20000,35,4] -> out[20000,35,128]
// out[:, :, :64]  = relu(BN(aug @ W^T + b)),  aug = [v, v[:3]-mean3]
// out[:, :, 64:]  = broadcast(max over T of first half)
//
// Algebra: dot(w_c, aug_t) = dot(weff_c, v_t) - dot(wrel_c, mean3)
//   weff_c[j] = w[c][j] + (j<3 ? w[c][4+j] : 0), wrel_c = w[c][4:7]
// BN batch stats exact via 7x7 second-moment matrix of aug (linearity of the
// 7->64 layer): pass 1 touches only the 11 MB input, reduces 35 floats.
//
// R3 changes: bnparams partial-reduction parallelized (was 1 wave x 256
// serialized strided loads ~ 60 us on one CU); stats voxel loads software-
// pipelined; encode uses nontemporal float4 stores (pure streaming output).
// R3b: nontemporal stores need clang ext_vector type, not HIP float4 class.

#define NVOX   20000
#define TDIM   35
#define NCH    128
#define HID    64
#define NTF    700000.0f      // N*T, exact in fp32
#define EPS    1e-5f
#define NBLK_A 256
#define PARAM_OFF (NBLK_A * 35)   // ws floats: [35][NBLK_A] partials, then [64][8] params

typedef float nt4 __attribute__((ext_vector_type(4)));  // for nontemporal stores

// ---------------- pass 1: per-block partial [M2(28) | s(7)] ----------------
// partial layout TRANSPOSED: ws[i * NBLK_A + blockIdx] so pass 2 reads contiguous.
__global__ __launch_bounds__(256) void vfe_stats(const float* __restrict__ vox,
                                                 float* __restrict__ ws) {
  const int lane = threadIdx.x & 63;
  const int wid  = threadIdx.x >> 6;
  const int gwave  = (blockIdx.x * 256 + threadIdx.x) >> 6;
  const int nwaves = NBLK_A * 4;

  float m2[28], sv[7];
#pragma unroll
  for (int i = 0; i < 28; ++i) m2[i] = 0.f;
#pragma unroll
  for (int i = 0; i < 7; ++i) sv[i] = 0.f;

  // software pipeline: load voxel n+stride while reducing voxel n
  float4 row = make_float4(0.f, 0.f, 0.f, 0.f);
  if (lane < TDIM) row = *(const float4*)(vox + (size_t)gwave * (TDIM * 4) + lane * 4);

  for (int n = gwave; n < NVOX; n += nwaves) {
    const int nn = n + nwaves;
    float4 nxt = make_float4(0.f, 0.f, 0.f, 0.f);
    if (nn < NVOX && lane < TDIM)
      nxt = *(const float4*)(vox + (size_t)nn * (TDIM * 4) + lane * 4);

    float rowsum = (row.x + row.y) + (row.z + row.w);
    float cnt = (float)__popcll(__ballot((lane < TDIM) && (rowsum != 0.f)));
    float s0 = row.x, s1 = row.y, s2 = row.z;
#pragma unroll
    for (int off = 32; off; off >>= 1) {
      s0 += __shfl_down(s0, off);
      s1 += __shfl_down(s1, off);
      s2 += __shfl_down(s2, off);
    }
    float rc = 1.f / cnt;
    float mx = __shfl(s0, 0) * rc;
    float my = __shfl(s1, 0) * rc;
    float mz = __shfl(s2, 0) * rc;
    if (lane < TDIM) {
      float a[7] = {row.x, row.y, row.z, row.w, row.x - mx, row.y - my, row.z - mz};
      int idx = 0;
#pragma unroll
      for (int j = 0; j < 7; ++j) {
        sv[j] += a[j];
#pragma unroll
        for (int k = j; k < 7; ++k) { m2[idx] = fmaf(a[j], a[k], m2[idx]); ++idx; }
      }
    }
    row = nxt;
  }

  __shared__ float part[4][35];
#pragma unroll
  for (int i = 0; i < 35; ++i) {
    float v = (i < 28) ? m2[i] : sv[i - 28];
#pragma unroll
    for (int off = 32; off; off >>= 1) v += __shfl_down(v, off);
    if (lane == 0) part[wid][i] = v;
  }
  __syncthreads();
  if (threadIdx.x < 35)
    ws[threadIdx.x * NBLK_A + blockIdx.x] =
        part[0][threadIdx.x] + part[1][threadIdx.x] +
        part[2][threadIdx.x] + part[3][threadIdx.x];
}

// -- pass 2: BN stats -> per-channel folded params. 320 threads: the 256
// partials per stat are reduced by 8 threads x 8 contiguous float4 loads.
__global__ __launch_bounds__(320) void vfe_bnparams(const float* __restrict__ W,
                             const float* __restrict__ b,
                             const float* __restrict__ gamma, const float* __restrict__ beta,
                             float* __restrict__ ws) {
  __shared__ float part[35][8];
  __shared__ float stats[35];
  const int tid = threadIdx.x;

  if (tid < 280) {
    const int i = tid >> 3, g = tid & 7;
    const float4* src = (const float4*)(ws + i * NBLK_A + g * 32);
    float acc = 0.f;
#pragma unroll
    for (int q = 0; q < 8; ++q) {
      float4 v = src[q];
      acc += (v.x + v.y) + (v.z + v.w);
    }
    part[i][g] = acc;
  }
  __syncthreads();
  if (tid < 35) {
    float a = 0.f;
#pragma unroll
    for (int g = 0; g < 8; ++g) a += part[tid][g];
    stats[tid] = a;
  }
  __syncthreads();
  if (tid >= 64) return;

  const int c = tid;
  float m2[7][7];
  {
    int idx = 0;
    for (int j = 0; j < 7; ++j)
      for (int k = j; k < 7; ++k) { float v = stats[idx++]; m2[j][k] = v; m2[k][j] = v; }
  }
  float w[7];
#pragma unroll
  for (int j = 0; j < 7; ++j) w[j] = W[c * 7 + j];
  float bc = b[c];

  float wdots = 0.f;
#pragma unroll
  for (int j = 0; j < 7; ++j) wdots = fmaf(w[j], stats[28 + j], wdots);
  float q = 0.f;
#pragma unroll
  for (int j = 0; j < 7; ++j) {
    float t = 0.f;
#pragma unroll
    for (int k = 0; k < 7; ++k) t = fmaf(w[k], m2[j][k], t);
    q = fmaf(w[j], t, q);
  }
  float sx  = wdots + NTF * bc;                       // sum x_c
  float sxx = q + 2.f * bc * wdots + NTF * bc * bc;   // sum x_c^2
  float mu  = sx / NTF;
  float var = sxx / NTF - mu * mu;                    // biased, as reference
  float scale = gamma[c] / sqrtf(var + EPS);
  float shift = beta[c] + scale * (bc - mu);          // linear bias folded in

  float* p = ws + PARAM_OFF + c * 8;
  p[0] = scale * (w[0] + w[4]);
  p[1] = scale * (w[1] + w[5]);
  p[2] = scale * (w[2] + w[6]);
  p[3] = scale * w[3];
  p[4] = scale * w[4];
  p[5] = scale * w[5];
  p[6] = scale * w[6];
  p[7] = shift;
}

// ---- pass 3: wave/voxel, lane=(tgroup, 4-channel group), nt float4 stores ----
__global__ __launch_bounds__(256) void vfe_encode(const float* __restrict__ vox,
                                                  const float* __restrict__ ws,
                                                  float* __restrict__ out) {
  const int lane = threadIdx.x & 63;
  const int wid  = threadIdx.x >> 6;
  const int n = (blockIdx.x * 256 + threadIdx.x) >> 6;

  __shared__ float4 rows[4][64];

  float4 row = make_float4(0.f, 0.f, 0.f, 0.f);
  if (lane < TDIM) row = *(const float4*)(vox + (size_t)n * (TDIM * 4) + lane * 4);
  float rowsum = (row.x + row.y) + (row.z + row.w);
  float cnt = (float)__popcll(__ballot((lane < TDIM) && (rowsum != 0.f)));
  float s0 = row.x, s1 = row.y, s2 = row.z;
#pragma unroll
  for (int off = 32; off; off >>= 1) {
    s0 += __shfl_down(s0, off);
    s1 += __shfl_down(s1, off);
    s2 += __shfl_down(s2, off);
  }
  float rc = 1.f / cnt;
  const float mx = __shfl(s0, 0) * rc;
  const float my = __shfl(s1, 0) * rc;
  const float mz = __shfl(s2, 0) * rc;

  rows[wid][lane] = row;
  __syncthreads();

  const int tg = lane >> 4;          // which t mod 4
  const int c4 = (lane & 15) << 2;   // first of 4 channels

  // per-channel folded params: wv = scale*weff (4), wr.xyz = scale*wrel, wr.w = shift
  const float4* pars = (const float4*)(ws + PARAM_OFF);
  float4 wv[4], wr[4];
  float base[4], agg[4];
#pragma unroll
  for (int i = 0; i < 4; ++i) {
    wv[i] = pars[(c4 + i) * 2];
    wr[i] = pars[(c4 + i) * 2 + 1];
    base[i] = wr[i].w - (wr[i].x * mx + wr[i].y * my + wr[i].z * mz);
    agg[i] = 0.f;  // post-ReLU values >= 0
  }

  float* op = out + (size_t)n * (TDIM * NCH);
#pragma unroll
  for (int k = 0; k < 9; ++k) {
    const int t = 4 * k + tg;
    if (t < TDIM) {
      float4 v = rows[wid][t];
      float y[4];
#pragma unroll
      for (int i = 0; i < 4; ++i) {
        float d = fmaf(wv[i].x, v.x, base[i]);
        d = fmaf(wv[i].y, v.y, d);
        d = fmaf(wv[i].z, v.z, d);
        d = fmaf(wv[i].w, v.w, d);
        d = fmaxf(d, 0.f);
        agg[i] = fmaxf(agg[i], d);
        y[i] = d;
      }
      nt4 yv = {y[0], y[1], y[2], y[3]};
      __builtin_nontemporal_store(yv, (nt4*)(op + t * NCH + c4));
    }
  }

  // max across the 4 t-groups holding the same channels (lanes ^16, ^32)
#pragma unroll
  for (int i = 0; i < 4; ++i) {
    agg[i] = fmaxf(agg[i], __shfl_xor(agg[i], 16));
    agg[i] = fmaxf(agg[i], __shfl_xor(agg[i], 32));
  }
  const nt4 av = {agg[0], agg[1], agg[2], agg[3]};
#pragma unroll
  for (int k = 0; k < 9; ++k) {
    const int t = 4 * k + tg;
    if (t < TDIM)
      __builtin_nontemporal_store(av, (nt4*)(op + t * NCH + HID + c4));
  }
}

extern "C" void kernel_launch(void* const* d_in, const int* in_sizes, int n_in,
                              void* d_out, int out_size, void* d_ws, size_t ws_size,
                              hipStream_t stream) {
  const float* vox   = (const float*)d_in[0];
  const float* W     = (const float*)d_in[1];
  const float* b     = (const float*)d_in[2];
  const float* gamma = (const float*)d_in[3];
  const float* beta  = (const float*)d_in[4];
  float* out = (float*)d_out;
  float* ws  = (float*)d_ws;

  vfe_stats<<<NBLK_A, 256, 0, stream>>>(vox, ws);
  vfe_bnparams<<<1, 320, 0, stream>>>(W, b, gamma, beta, ws);
  vfe_encode<<<NVOX / 4, 256, 0, stream>>>(vox, ws, out);
}